// Round 3
// baseline (7290.220 us; speedup 1.0000x reference)
//
#include <hip/hip_runtime.h>
#include <stdint.h>

typedef unsigned int u32;
typedef unsigned long long u64;

#define CB 8
#define CT 512
#define CDIM 512
#define CR 2048
#define CH 8
#define CHD 64
#define CFFMAX 1368        // upper bound for workspace sizing only; real FF from in_sizes
#define CM 4096            // B*T
#define SCAN_WGS 64

// ======================= |w| sums (for ternary thresholds) =======================
__global__ __launch_bounds__(256) void k_abssum(const float* __restrict__ w, long n,
                                                double* __restrict__ sums, int idx){
  double s = 0.0;
  long stride = (long)gridDim.x * blockDim.x;
  for (long i = (long)blockIdx.x*blockDim.x + threadIdx.x; i < n; i += stride)
    s += (double)fabsf(w[i]);
  #pragma unroll
  for (int d = 32; d; d >>= 1) s += __shfl_down(s, d);
  __shared__ double ps[4];
  int lane = threadIdx.x & 63, wv = threadIdx.x >> 6;
  if (lane == 0) ps[wv] = s;
  __syncthreads();
  if (threadIdx.x == 0) atomicAdd(&sums[idx], ps[0]+ps[1]+ps[2]+ps[3]);
}

// ======================= ternary decode to f32 {-1,0,1} =======================
__global__ __launch_bounds__(256) void k_decode(const float* __restrict__ w, float* __restrict__ q,
                                                long n, const double* __restrict__ sums, int idx, double invN){
  double thr = 0.7 * (sums[idx] * invN);
  long stride = (long)gridDim.x * blockDim.x;
  for (long i = (long)blockIdx.x*blockDim.x + threadIdx.x; i < n; i += stride){
    float v = w[i];
    q[i] = (fabs((double)v) > thr) ? (v > 0.0f ? 1.0f : -1.0f) : 0.0f;
  }
}

// decode + transpose: w[rows][cols] -> qT[cols][rows]   (used for Wi)
__global__ __launch_bounds__(256) void k_decodeT(const float* __restrict__ w, float* __restrict__ qT,
                                                 long rows, long cols, const double* __restrict__ sums,
                                                 int idx, double invN){
  double thr = 0.7 * (sums[idx] * invN);
  long n = rows * cols;
  long stride = (long)gridDim.x * blockDim.x;
  for (long i = (long)blockIdx.x*blockDim.x + threadIdx.x; i < n; i += stride){
    long r = i / cols, d = i - r*cols;
    float v = w[i];
    float o = (fabs((double)v) > thr) ? (v > 0.0f ? 1.0f : -1.0f) : 0.0f;
    qT[d*rows + r] = o;
  }
}

// ======================= xp = x @ ternary(Wi)^T + bi   (float64 exact) =======================
// output layout xp[t][r][b]  (f64)
__global__ __launch_bounds__(256) void k_xp(const float* __restrict__ x, const float* __restrict__ wiqT,
                                            const float* __restrict__ bi, double* __restrict__ xp){
  int t = blockIdx.y;
  int r = blockIdx.x*256 + threadIdx.x;
  __shared__ double xs[CB][CDIM];          // 32 KB
  for (int i = threadIdx.x; i < CB*CDIM; i += 256){
    int b = i >> 9, d = i & 511;
    xs[b][d] = (double)x[((size_t)b*CT + t)*CDIM + d];
  }
  __syncthreads();
  double acc[CB];
  #pragma unroll
  for (int b = 0; b < CB; ++b) acc[b] = 0.0;
  for (int d = 0; d < CDIM; ++d){
    double wd = (double)wiqT[(size_t)d*CR + r];
    #pragma unroll
    for (int b = 0; b < CB; ++b) acc[b] = fma(wd, xs[b][d], acc[b]);
  }
  double bd = (double)bi[r];
  double* o = xp + ((size_t)t*CR + r)*CB;
  #pragma unroll
  for (int b = 0; b < CB; ++b) o[b] = acc[b] + bd;
}

// ======================= LIF reservoir scan =======================
// 64 WGs x 256 threads, WG g owns neurons [32g,32g+32). thread=(row=tid>>3, k=tid&7).
// Wr ternary masks hoisted to REGISTERS (loop-invariant, 8 u64/thread).
// Sync: stamped data-flow publication (u64 = spikes|stamp<<32), parity double-buffered;
// consumers poll the words they need — no centralized barrier.
// Skew proof: WG publishes t+1 only after consuming all stamps t, so a slot of parity p
// cannot be overwritten (stamp t+2) before all consumers read stamp t. Stale stamps from
// a previous (deterministic, identical-input) run either mismatch or carry identical data.
__global__ __launch_bounds__(256) void k_scan(const float* __restrict__ Wr,
                                              const double* __restrict__ xp,
                                              const float* __restrict__ beta,
                                              const float* __restrict__ sfi,
                                              const float* __restrict__ sfd,
                                              const double* __restrict__ sums,
                                              u32* __restrict__ acts,
                                              u64* __restrict__ pub){
  __shared__ u32 spk32[CB][64];            // previous-step spikes, 2 KB
  __shared__ unsigned char sbyte[CB][32];
  int tid = threadIdx.x;
  int g = blockIdx.x;
  int rbase = g * 32;
  int row = tid >> 3, k = tid & 7;
  double thr = 0.7 * (sums[1] * (1.0/((double)CR*(double)CR)));
  // build this thread's 4 (pos,neg) mask pairs in registers: words w = k + 8j
  u64 mpos[4], mneg[4];
  #pragma unroll
  for (int j = 0; j < 4; ++j){
    int w = k + 8*j;
    const float* wr = Wr + ((size_t)(rbase+row))*CR + w*64;
    u64 pos = 0, neg = 0;
    for (int jj = 0; jj < 64; jj += 4){
      float4 v4 = *reinterpret_cast<const float4*>(wr + jj);
      float vv[4] = {v4.x, v4.y, v4.z, v4.w};
      #pragma unroll
      for (int c = 0; c < 4; ++c){
        if (fabs((double)vv[c]) > thr){
          if (vv[c] > 0.0f) pos |= (1ull << (jj + c));
          else              neg |= (1ull << (jj + c));
        }
      }
    }
    mpos[j] = pos; mneg[j] = neg;
  }
  // zero previous-spike staging (step -1 = no spikes)
  spk32[tid >> 6][tid & 63] = 0;
  spk32[(tid + 256) >> 6][tid & 63] = 0;
  int r = rbase + row;
  double mem = 0.0, ath = 0.0;
  double bt = (double)beta[r], dc = (double)sfd[r], ic = (double)sfi[r];
  const double* xpr = xp + (size_t)r*CB + k;
  int pb = tid >> 6, pg = tid & 63;        // this thread polls (pb,pg) and (pb+4,pg)
  __syncthreads();
  double xv = xpr[0];
  for (int t = 0; t < CT; ++t){
    double xv_next = (t+1 < CT) ? xpr[(size_t)(t+1)*CR*CB] : 0.0;
    int pa[8] = {0,0,0,0,0,0,0,0};
    int na[8] = {0,0,0,0,0,0,0,0};
    #pragma unroll
    for (int j = 0; j < 4; ++j){
      int w = k + 8*j;
      #pragma unroll
      for (int b = 0; b < CB; ++b){
        u64 s = *reinterpret_cast<const u64*>(&spk32[b][2*w]);  // broadcast (same addr per k)
        pa[b] += __popcll(s & mpos[j]);
        na[b] += __popcll(s & mneg[j]);
      }
    }
    int rec[8];
    #pragma unroll
    for (int b = 0; b < CB; ++b) rec[b] = pa[b] - na[b];
    #pragma unroll
    for (int b = 0; b < CB; ++b) rec[b] += __shfl_xor(rec[b], 1);
    #pragma unroll
    for (int b = 0; b < CB; ++b) rec[b] += __shfl_xor(rec[b], 2);
    #pragma unroll
    for (int b = 0; b < CB; ++b) rec[b] += __shfl_xor(rec[b], 4);
    // f64 LIF update (bit-matches numpy-f64 reference trajectory)
    double cur = xv + (double)rec[k];
    mem = bt*mem + cur;
    bool sp = (mem - (1.0 + ath)) > 0.0;
    mem = sp ? 0.0 : mem;
    ath = dc*ath + (sp ? ic : 0.0);
    sbyte[k][row] = sp ? (unsigned char)1 : (unsigned char)0;
    xv = xv_next;
    __syncthreads();
    if (tid < CB){
      const u32* sb = reinterpret_cast<const u32*>(&sbyte[tid][0]);
      u32 word = 0;
      #pragma unroll
      for (int i = 0; i < 8; ++i){
        u32 wv = sb[i];
        word |= ((wv & 1u) | ((wv >> 7) & 2u) | ((wv >> 14) & 4u) | ((wv >> 21) & 8u)) << (4*i);
      }
      acts[((size_t)tid*CT + t)*64 + g] = word;
      u64 val = (u64)word | ((u64)(u32)(t+1) << 32);
      __hip_atomic_store(&pub[((size_t)((t+1)&1)*CB + tid)*64 + g], val,
                         __ATOMIC_RELEASE, __HIP_MEMORY_SCOPE_AGENT);
    }
    // poll the two stamped words this thread owns, stage into spk32
    {
      int par = (t+1) & 1;
      u64* a1 = &pub[((size_t)par*CB + pb)*64 + pg];
      u64* a2 = &pub[((size_t)par*CB + pb+4)*64 + pg];
      u64 v1 = 0, v2 = 0;
      bool d1 = false, d2 = false;
      while (!(d1 && d2)){
        if (!d1){ v1 = __hip_atomic_load(a1, __ATOMIC_ACQUIRE, __HIP_MEMORY_SCOPE_AGENT);
                  d1 = ((u32)(v1 >> 32) == (u32)(t+1)); }
        if (!d2){ v2 = __hip_atomic_load(a2, __ATOMIC_ACQUIRE, __HIP_MEMORY_SCOPE_AGENT);
                  d2 = ((u32)(v2 >> 32) == (u32)(t+1)); }
        if (!(d1 && d2)) __builtin_amdgcn_s_sleep(1);
      }
      spk32[pb][pg]     = (u32)v1;
      spk32[pb + 4][pg] = (u32)v2;
    }
    __syncthreads();
  }
}

// ======================= hn = rmsnorm(acts) * rn_w  (spikes are 0/1) =======================
__global__ __launch_bounds__(256) void k_hn(const u32* __restrict__ acts, const float* __restrict__ rn_w,
                                            float* __restrict__ hn){
  int rowbt = blockIdx.x;
  int b = rowbt >> 9, t = rowbt & 511;
  __shared__ u32 wlds[64];
  __shared__ int pc[64];
  __shared__ float sS;
  int tid = threadIdx.x;
  const u32* src = acts + ((size_t)b*CT + t)*64;
  if (tid < 64){ u32 w = src[tid]; wlds[tid] = w; pc[tid] = __popc(w); }
  __syncthreads();
  if (tid == 0){
    int c = 0;
    for (int i = 0; i < 64; ++i) c += pc[i];
    sS = 1.0f / sqrtf((float)c * (1.0f/(float)CR) + 1e-6f);
  }
  __syncthreads();
  float s = sS;
  #pragma unroll
  for (int i = 0; i < 8; ++i){
    int r = tid + 256*i;
    u32 w = wlds[r >> 5];
    float v = ((w >> (r & 31)) & 1u) ? s * rn_w[r] : 0.0f;
    hn[(size_t)rowbt*CR + r] = v;
  }
}

// ======================= generic f32 tiled GEMM, 128x128 tile, 8x8/thread =======================
// EPI: 0 none, 1 +bias->gelu, 2 +bias, 3 silu, 4 +res
struct GemmP {
  const float* A; long lda, Ab, Ah;
  const float* B; long ldb, Bb, Bh;
  float* C;       long ldc, Cb, Ch;
  const float* bias;
  const float* res; long ldr, Rb, Rh;
  float scale;
  int M, N, K, HH;
};

template<int EPI, bool BT>
__global__ __launch_bounds__(256) void k_gemm(GemmP p){
  int bz = blockIdx.z;
  int bb = bz / p.HH, hh = bz - bb*p.HH;
  const float* A = p.A + (size_t)bb*p.Ab + (size_t)hh*p.Ah;
  const float* B = p.B + (size_t)bb*p.Bb + (size_t)hh*p.Bh;
  float* C = p.C + (size_t)bb*p.Cb + (size_t)hh*p.Ch;
  const float* R = p.res ? (p.res + (size_t)bb*p.Rb + (size_t)hh*p.Rh) : (const float*)0;
  int m0 = blockIdx.y*128, n0 = blockIdx.x*128;
  __shared__ float As[16][132];
  __shared__ float Bs[16][132];
  int tid = threadIdx.x;
  int tx = tid & 15, ty = tid >> 4;
  bool a4 = ((p.lda & 3) == 0);
  bool b4 = ((p.ldb & 3) == 0);
  float acc[8][8];
  #pragma unroll
  for (int i = 0; i < 8; ++i)
    #pragma unroll
    for (int j = 0; j < 8; ++j) acc[i][j] = 0.0f;
  for (int k0 = 0; k0 < p.K; k0 += 16){
    // ---- A tile: 128 m x 16 k ----
    {
      int mr = tid >> 2, kc = (tid & 3)*4;
      #pragma unroll
      for (int ps = 0; ps < 2; ++ps){
        int mm = mr + ps*64, gm = m0 + mm, gk = k0 + kc;
        float4 v = make_float4(0.f,0.f,0.f,0.f);
        if (gm < p.M){
          if (a4 && (gk + 3 < p.K)) v = *reinterpret_cast<const float4*>(&A[(size_t)gm*p.lda + gk]);
          else {
            float tv[4];
            #pragma unroll
            for (int c = 0; c < 4; ++c) tv[c] = (gk+c < p.K) ? A[(size_t)gm*p.lda + gk + c] : 0.0f;
            v = make_float4(tv[0],tv[1],tv[2],tv[3]);
          }
        }
        As[kc+0][mm] = v.x; As[kc+1][mm] = v.y; As[kc+2][mm] = v.z; As[kc+3][mm] = v.w;
      }
    }
    // ---- B tile ----
    if (BT){
      int nr = tid >> 2, kc = (tid & 3)*4;
      #pragma unroll
      for (int ps = 0; ps < 2; ++ps){
        int nn = nr + ps*64, gn = n0 + nn, gk = k0 + kc;
        float4 v = make_float4(0.f,0.f,0.f,0.f);
        if (gn < p.N){
          if (b4 && (gk + 3 < p.K)) v = *reinterpret_cast<const float4*>(&B[(size_t)gn*p.ldb + gk]);
          else {
            float tv[4];
            #pragma unroll
            for (int c = 0; c < 4; ++c) tv[c] = (gk+c < p.K) ? B[(size_t)gn*p.ldb + gk + c] : 0.0f;
            v = make_float4(tv[0],tv[1],tv[2],tv[3]);
          }
        }
        Bs[kc+0][nn] = v.x; Bs[kc+1][nn] = v.y; Bs[kc+2][nn] = v.z; Bs[kc+3][nn] = v.w;
      }
    } else {
      int kr = tid >> 5, nc = (tid & 31)*4;
      #pragma unroll
      for (int ps = 0; ps < 2; ++ps){
        int kk = kr + ps*8, gk = k0 + kk, gn = n0 + nc;
        float4 v = make_float4(0.f,0.f,0.f,0.f);
        if (gk < p.K){
          if (b4 && (gn + 3 < p.N)) v = *reinterpret_cast<const float4*>(&B[(size_t)gk*p.ldb + gn]);
          else {
            float tv[4];
            #pragma unroll
            for (int c = 0; c < 4; ++c) tv[c] = (gn+c < p.N) ? B[(size_t)gk*p.ldb + gn + c] : 0.0f;
            v = make_float4(tv[0],tv[1],tv[2],tv[3]);
          }
        }
        *reinterpret_cast<float4*>(&Bs[kk][nc]) = v;
      }
    }
    __syncthreads();
    #pragma unroll
    for (int kk = 0; kk < 16; ++kk){
      float a[8], b[8];
      *reinterpret_cast<float4*>(&a[0]) = *reinterpret_cast<const float4*>(&As[kk][ty*8]);
      *reinterpret_cast<float4*>(&a[4]) = *reinterpret_cast<const float4*>(&As[kk][ty*8+4]);
      *reinterpret_cast<float4*>(&b[0]) = *reinterpret_cast<const float4*>(&Bs[kk][tx*8]);
      *reinterpret_cast<float4*>(&b[4]) = *reinterpret_cast<const float4*>(&Bs[kk][tx*8+4]);
      #pragma unroll
      for (int i = 0; i < 8; ++i)
        #pragma unroll
        for (int j = 0; j < 8; ++j)
          acc[i][j] = fmaf(a[i], b[j], acc[i][j]);
    }
    __syncthreads();
  }
  #pragma unroll
  for (int i = 0; i < 8; ++i){
    int gm = m0 + ty*8 + i;
    if (gm >= p.M) continue;
    #pragma unroll
    for (int j = 0; j < 8; ++j){
      int gn = n0 + tx*8 + j;
      if (gn >= p.N) continue;
      float v = acc[i][j] * p.scale;
      if (EPI == 1){ v += p.bias[gn]; v = 0.5f*v*(1.0f + erff(v*0.7071067811865475f)); }
      else if (EPI == 2){ v += p.bias[gn]; }
      else if (EPI == 3){ v = v / (1.0f + expf(-v)); }
      else if (EPI == 4){ v += R[(size_t)gm*p.ldr + gn]; }
      C[(size_t)gm*p.ldc + gn] = v;
    }
  }
}

template<int EPI, bool BT>
static void run_gemm(const GemmP& p, hipStream_t s, int nbat){
  dim3 grid((p.N + 127)/128, (p.M + 127)/128, nbat), blk(256);
  k_gemm<EPI, BT><<<grid, blk, 0, s>>>(p);
}

// ======================= row softmax (512 cols), in place =======================
__global__ __launch_bounds__(256) void k_softmax(float* __restrict__ sc, long rows){
  long gw = ((long)blockIdx.x*blockDim.x + threadIdx.x) >> 6;
  int lane = threadIdx.x & 63;
  if (gw >= rows) return;
  float* row = sc + gw*512;
  float4 v1 = *reinterpret_cast<const float4*>(row + lane*8);
  float4 v2 = *reinterpret_cast<const float4*>(row + lane*8 + 4);
  float v[8] = {v1.x, v1.y, v1.z, v1.w, v2.x, v2.y, v2.z, v2.w};
  float mx = v[0];
  #pragma unroll
  for (int e = 1; e < 8; ++e) mx = fmaxf(mx, v[e]);
  #pragma unroll
  for (int d = 32; d; d >>= 1) mx = fmaxf(mx, __shfl_xor(mx, d));
  float sum = 0.0f;
  #pragma unroll
  for (int e = 0; e < 8; ++e){ v[e] = expf(v[e] - mx); sum += v[e]; }
  #pragma unroll
  for (int d = 32; d; d >>= 1) sum += __shfl_xor(sum, d);
  float inv = 1.0f / sum;
  float4 o1 = make_float4(v[0]*inv, v[1]*inv, v[2]*inv, v[3]*inv);
  float4 o2 = make_float4(v[4]*inv, v[5]*inv, v[6]*inv, v[7]*inv);
  *reinterpret_cast<float4*>(row + lane*8) = o1;
  *reinterpret_cast<float4*>(row + lane*8 + 4) = o2;
}

// ======================= rmsnorm rows of 512 =======================
__global__ __launch_bounds__(256) void k_rmsnorm(const float* __restrict__ x, const float* __restrict__ w,
                                                 float* __restrict__ o, long rows){
  long gw = ((long)blockIdx.x*blockDim.x + threadIdx.x) >> 6;
  int lane = threadIdx.x & 63;
  if (gw >= rows) return;
  const float* xr = x + gw*512;
  float v[8]; float ss = 0.0f;
  #pragma unroll
  for (int e = 0; e < 8; ++e){ v[e] = xr[lane*8 + e]; ss = fmaf(v[e], v[e], ss); }
  #pragma unroll
  for (int d = 32; d; d >>= 1) ss += __shfl_xor(ss, d);
  float r = 1.0f / sqrtf(ss*(1.0f/512.0f) + 1e-6f);
  float* orow = o + gw*512;
  #pragma unroll
  for (int e = 0; e < 8; ++e) orow[lane*8 + e] = v[e]*r*w[lane*8 + e];
}

// ======================= elementwise g *= u =======================
__global__ __launch_bounds__(256) void k_mul(float* __restrict__ g, const float* __restrict__ u, long n){
  long stride = (long)gridDim.x * blockDim.x;
  for (long i = (long)blockIdx.x*blockDim.x + threadIdx.x; i < n; i += stride) g[i] *= u[i];
}

// ======================= host =======================
extern "C" void kernel_launch(void* const* d_in, const int* in_sizes, int n_in,
                              void* d_out, int out_size, void* d_ws, size_t ws_size,
                              hipStream_t stream){
  (void)n_in; (void)out_size;
  const float* x    = (const float*)d_in[0];
  const float* Wi   = (const float*)d_in[1];
  const float* bi   = (const float*)d_in[2];
  const float* Wr   = (const float*)d_in[3];
  const float* rn_w = (const float*)d_in[4];
  const float* W1   = (const float*)d_in[5];
  const float* b1   = (const float*)d_in[6];
  const float* W2   = (const float*)d_in[7];
  const float* b2   = (const float*)d_in[8];
  const float* anw  = (const float*)d_in[9];
  const float* Wqkv = (const float*)d_in[10];
  const float* Wo   = (const float*)d_in[11];
  const float* fnw  = (const float*)d_in[12];
  const float* Wf1  = (const float*)d_in[13];
  const float* Wf2  = (const float*)d_in[14];
  const float* Wf3  = (const float*)d_in[15];
  const float* beta = (const float*)d_in[16];
  const float* sfi  = (const float*)d_in[17];
  const float* sfd  = (const float*)d_in[18];

  // FFH = int(DIM*2.66) = 1361 (reference comment says 1362 — wrong). Derive from input.
  const long FF = (long)in_sizes[13] / CDIM;

  char* ws = (char*)d_ws;
  size_t cur = 0;
  auto alloc = [&](size_t bytes){ size_t o = cur; cur += (bytes + 255) & ~(size_t)255; return o; };
  size_t oCTRL = alloc(4096);
  size_t oPUB  = alloc((size_t)2*CB*64*8);             // 8 KB stamped spike publication
  size_t oACTS = alloc((size_t)CB*CT*64*4);            // 1 MB  spike bits
  size_t oXP   = alloc((size_t)CT*CR*CB*8);            // 64 MB f64 xp; reused as scores f32
  size_t oWIQT = alloc((size_t)CDIM*CR*4);
  size_t oW1Q  = alloc((size_t)1024*CR*4);
  size_t oW2Q  = alloc((size_t)512*1024*4);
  size_t oWQKV = alloc((size_t)1536*512*4);
  size_t oWOQ  = alloc((size_t)512*512*4);
  size_t oWF1Q = alloc((size_t)CFFMAX*512*4);
  size_t oWF2Q = alloc((size_t)512*CFFMAX*4);
  size_t oWF3Q = alloc((size_t)CFFMAX*512*4);
  size_t oHN   = alloc((size_t)CM*CR*4);               // hn; reused as g
  size_t oH    = alloc((size_t)CM*1024*4);
  size_t oY    = alloc((size_t)CM*512*4);
  size_t oXA   = alloc((size_t)CM*512*4);              // xa; reused as xf
  size_t oQKV  = alloc((size_t)CM*1536*4);             // qkv; reused as u
  size_t oO    = alloc((size_t)CM*512*4);
  size_t oXR   = alloc((size_t)CM*512*4);
  if (cur > ws_size) return;

  double* sums = (double*)(ws + oCTRL + 128);
  u64* pub = (u64*)(ws + oPUB);
  u32* uACTS = (u32*)(ws + oACTS);
  double* dXP = (double*)(ws + oXP);
  float* fSC  = (float*)(ws + oXP);
  float* fWIQT = (float*)(ws + oWIQT);
  float* fW1Q = (float*)(ws + oW1Q);
  float* fW2Q = (float*)(ws + oW2Q);
  float* fWQKV = (float*)(ws + oWQKV);
  float* fWOQ = (float*)(ws + oWOQ);
  float* fWF1Q = (float*)(ws + oWF1Q);
  float* fWF2Q = (float*)(ws + oWF2Q);
  float* fWF3Q = (float*)(ws + oWF3Q);
  float* fHN = (float*)(ws + oHN);
  float* fG  = (float*)(ws + oHN);
  float* fH  = (float*)(ws + oH);
  float* fY  = (float*)(ws + oY);
  float* fXA = (float*)(ws + oXA);
  float* fQKV = (float*)(ws + oQKV);
  float* fU  = (float*)(ws + oQKV);
  float* fO  = (float*)(ws + oO);
  float* fXR = (float*)(ws + oXR);
  float* out = (float*)d_out;

  dim3 b256(256);
  hipMemsetAsync(ws + oCTRL, 0, 4096, stream);

  k_abssum<<<512, b256, 0, stream>>>(Wi,  (long)CR*CDIM,  sums, 0);
  k_abssum<<<512, b256, 0, stream>>>(Wr,  (long)CR*CR,    sums, 1);
  k_abssum<<<512, b256, 0, stream>>>(W1,  (long)1024*CR,  sums, 2);
  k_abssum<<<512, b256, 0, stream>>>(W2,  (long)512*1024, sums, 3);
  k_abssum<<<512, b256, 0, stream>>>(Wqkv,(long)1536*512, sums, 4);
  k_abssum<<<512, b256, 0, stream>>>(Wo,  (long)512*512,  sums, 5);
  k_abssum<<<512, b256, 0, stream>>>(Wf1, FF*512,         sums, 6);
  k_abssum<<<512, b256, 0, stream>>>(Wf2, 512*FF,         sums, 7);
  k_abssum<<<512, b256, 0, stream>>>(Wf3, FF*512,         sums, 8);

  k_decodeT<<<1024, b256, 0, stream>>>(Wi, fWIQT, CR, CDIM, sums, 0, 1.0/((double)CR*CDIM));
  k_decode<<<1024, b256, 0, stream>>>(W1,  fW1Q, (long)1024*CR,  sums, 2, 1.0/((double)1024*CR));
  k_decode<<<1024, b256, 0, stream>>>(W2,  fW2Q, (long)512*1024, sums, 3, 1.0/((double)512*1024));
  k_decode<<<1024, b256, 0, stream>>>(Wqkv,fWQKV,(long)1536*512, sums, 4, 1.0/((double)1536*512));
  k_decode<<<1024, b256, 0, stream>>>(Wo,  fWOQ, (long)512*512,  sums, 5, 1.0/((double)512*512));
  k_decode<<<1024, b256, 0, stream>>>(Wf1, fWF1Q, FF*512,        sums, 6, 1.0/((double)FF*512));
  k_decode<<<1024, b256, 0, stream>>>(Wf2, fWF2Q, 512*FF,        sums, 7, 1.0/((double)FF*512));
  k_decode<<<1024, b256, 0, stream>>>(Wf3, fWF3Q, FF*512,        sums, 8, 1.0/((double)FF*512));

  k_xp<<<dim3(CR/256, CT), b256, 0, stream>>>(x, fWIQT, bi, dXP);
  k_scan<<<SCAN_WGS, b256, 0, stream>>>(Wr, dXP, beta, sfi, sfd, sums, uACTS, pub);
  k_hn<<<CM, b256, 0, stream>>>(uACTS, rn_w, fHN);

  // h = gelu(hn @ W1q^T + b1)
  { GemmP p{fHN, CR,0,0,  fW1Q, CR,0,0,  fH, 1024,0,0,  b1,  (const float*)0,0,0,0, 1.0f, CM,1024,CR,1};
    run_gemm<1,true>(p, stream, 1); }
  // y = h @ W2q^T + b2
  { GemmP p{fH, 1024,0,0, fW2Q, 1024,0,0, fY, 512,0,0,  b2,  (const float*)0,0,0,0, 1.0f, CM,512,1024,1};
    run_gemm<2,true>(p, stream, 1); }
  k_rmsnorm<<<CM/4, b256, 0, stream>>>(fY, anw, fXA, CM);
  // qkv = xa @ Wqkv^T
  { GemmP p{fXA, 512,0,0, fWQKV, 512,0,0, fQKV, 1536,0,0, (const float*)0, (const float*)0,0,0,0, 1.0f, CM,1536,512,1};
    run_gemm<0,true>(p, stream, 1); }
  // scores[b,h] = q @ k^T * 0.125
  { GemmP p{fQKV,       1536, 786432, 64,
            fQKV + 512, 1536, 786432, 64,
            fSC,        512,  2097152, 262144,
            (const float*)0, (const float*)0,0,0,0, 0.125f, 512,512,64,CH};
    run_gemm<0,true>(p, stream, CB*CH); }
  k_softmax<<<(long)CB*CH*512/4, b256, 0, stream>>>(fSC, (long)CB*CH*512);
  // o[b,h] = attn @ v
  { GemmP p{fSC,         512,  2097152, 262144,
            fQKV + 1024, 1536, 786432,  64,
            fO,          512,  262144,  64,
            (const float*)0, (const float*)0,0,0,0, 1.0f, 512,64,512,CH};
    run_gemm<0,false>(p, stream, CB*CH); }
  // x_res = y + o @ Wo^T
  { GemmP p{fO, 512,0,0, fWOQ, 512,0,0, fXR, 512,0,0, (const float*)0, fY, 512,0,0, 1.0f, CM,512,512,1};
    run_gemm<4,true>(p, stream, 1); }
  k_rmsnorm<<<CM/4, b256, 0, stream>>>(fXR, fnw, fXA, CM);
  // g = silu(xf @ Wf1^T)
  { GemmP p{fXA, 512,0,0, fWF1Q, 512,0,0, fG, FF,0,0, (const float*)0, (const float*)0,0,0,0, 1.0f, CM,(int)FF,512,1};
    run_gemm<3,true>(p, stream, 1); }
  // u = xf @ Wf3^T
  { GemmP p{fXA, 512,0,0, fWF3Q, 512,0,0, fU, FF,0,0, (const float*)0, (const float*)0,0,0,0, 1.0f, CM,(int)FF,512,1};
    run_gemm<0,true>(p, stream, 1); }
  k_mul<<<2048, b256, 0, stream>>>(fG, fU, (long)CM*FF);
  // out = x_res + (g*u) @ Wf2^T
  { GemmP p{fG, FF,0,0, fWF2Q, FF,0,0, out, 512,0,0, (const float*)0, fXR, 512,0,0, 1.0f, CM,512,(int)FF,1};
    run_gemm<4,true>(p, stream, 1); }
}

// Round 5
// 4652.810 us; speedup vs baseline: 1.5668x; 1.5668x over previous
//
#include <hip/hip_runtime.h>
#include <stdint.h>

typedef unsigned int u32;
typedef unsigned long long u64;

#define CB 8
#define CT 512
#define CDIM 512
#define CR 2048
#define CH 8
#define CHD 64
#define CFFMAX 1368        // upper bound for workspace sizing only; real FF from in_sizes
#define CM 4096            // B*T
#define SCAN_WGS 64

// ======================= |w| sums (for ternary thresholds) =======================
__global__ __launch_bounds__(256) void k_abssum(const float* __restrict__ w, long n,
                                                double* __restrict__ sums, int idx){
  double s = 0.0;
  long stride = (long)gridDim.x * blockDim.x;
  for (long i = (long)blockIdx.x*blockDim.x + threadIdx.x; i < n; i += stride)
    s += (double)fabsf(w[i]);
  #pragma unroll
  for (int d = 32; d; d >>= 1) s += __shfl_down(s, d);
  __shared__ double ps[4];
  int lane = threadIdx.x & 63, wv = threadIdx.x >> 6;
  if (lane == 0) ps[wv] = s;
  __syncthreads();
  if (threadIdx.x == 0) atomicAdd(&sums[idx], ps[0]+ps[1]+ps[2]+ps[3]);
}

// ======================= ternary decode to f32 {-1,0,1} =======================
__global__ __launch_bounds__(256) void k_decode(const float* __restrict__ w, float* __restrict__ q,
                                                long n, const double* __restrict__ sums, int idx, double invN){
  double thr = 0.7 * (sums[idx] * invN);
  long stride = (long)gridDim.x * blockDim.x;
  for (long i = (long)blockIdx.x*blockDim.x + threadIdx.x; i < n; i += stride){
    float v = w[i];
    q[i] = (fabs((double)v) > thr) ? (v > 0.0f ? 1.0f : -1.0f) : 0.0f;
  }
}

// decode + transpose: w[rows][cols] -> qT[cols][rows]   (used for Wi)
__global__ __launch_bounds__(256) void k_decodeT(const float* __restrict__ w, float* __restrict__ qT,
                                                 long rows, long cols, const double* __restrict__ sums,
                                                 int idx, double invN){
  double thr = 0.7 * (sums[idx] * invN);
  long n = rows * cols;
  long stride = (long)gridDim.x * blockDim.x;
  for (long i = (long)blockIdx.x*blockDim.x + threadIdx.x; i < n; i += stride){
    long r = i / cols, d = i - r*cols;
    float v = w[i];
    float o = (fabs((double)v) > thr) ? (v > 0.0f ? 1.0f : -1.0f) : 0.0f;
    qT[d*rows + r] = o;
  }
}

// ======================= xp = x @ ternary(Wi)^T + bi   (float64 exact) =======================
// output layout xp[t][r][b]  (f64)
__global__ __launch_bounds__(256) void k_xp(const float* __restrict__ x, const float* __restrict__ wiqT,
                                            const float* __restrict__ bi, double* __restrict__ xp){
  int t = blockIdx.y;
  int r = blockIdx.x*256 + threadIdx.x;
  __shared__ double xs[CB][CDIM];          // 32 KB
  for (int i = threadIdx.x; i < CB*CDIM; i += 256){
    int b = i >> 9, d = i & 511;
    xs[b][d] = (double)x[((size_t)b*CT + t)*CDIM + d];
  }
  __syncthreads();
  double acc[CB];
  #pragma unroll
  for (int b = 0; b < CB; ++b) acc[b] = 0.0;
  for (int d = 0; d < CDIM; ++d){
    double wd = (double)wiqT[(size_t)d*CR + r];
    #pragma unroll
    for (int b = 0; b < CB; ++b) acc[b] = fma(wd, xs[b][d], acc[b]);
  }
  double bd = (double)bi[r];
  double* o = xp + ((size_t)t*CR + r)*CB;
  #pragma unroll
  for (int b = 0; b < CB; ++b) o[b] = acc[b] + bd;
}

// ======================= LIF reservoir scan =======================
// 64 WGs x 256 threads, WG g owns neurons [32g,32g+32). thread=(row=tid>>3, k=tid&7).
// Wr ternary masks in REGISTERS. Sync per step: per-WG monotonic arrive flag
// (plain data stores -> one agent-scope release store); only wave 0 polls
// (lane L polls flag[L]) => 4096 spinners on 64 lines, no RMW, no master hop.
// Data parity double-buffer: safe because WG sets arrive=t+1 only after staging
// data(t-1) out of pub, and a writer targets parity slot (t+2)&1 only after
// seeing all arrive>=t+1 (proven scheme from rounds 2-3).
__global__ __launch_bounds__(256) void k_scan(const float* __restrict__ Wr,
                                              const double* __restrict__ xp,
                                              const float* __restrict__ beta,
                                              const float* __restrict__ sfi,
                                              const float* __restrict__ sfd,
                                              const double* __restrict__ sums,
                                              u32* __restrict__ acts,
                                              u32* __restrict__ pub,
                                              u32* __restrict__ arrive){
  __shared__ u32 spk32[CB][64];            // previous-step spikes, 2 KB
  __shared__ unsigned char sbyte[CB][32];
  int tid = threadIdx.x;
  int g = blockIdx.x;
  int rbase = g * 32;
  int row = tid >> 3, k = tid & 7;
  double thr = 0.7 * (sums[1] * (1.0/((double)CR*(double)CR)));
  // build this thread's 4 (pos,neg) mask pairs in registers: words w = k + 8j
  u64 mpos[4], mneg[4];
  #pragma unroll
  for (int j = 0; j < 4; ++j){
    int w = k + 8*j;
    const float* wr = Wr + ((size_t)(rbase+row))*CR + w*64;
    u64 pos = 0, neg = 0;
    for (int jj = 0; jj < 64; jj += 4){
      float4 v4 = *reinterpret_cast<const float4*>(wr + jj);
      float vv[4] = {v4.x, v4.y, v4.z, v4.w};
      #pragma unroll
      for (int c = 0; c < 4; ++c){
        if (fabs((double)vv[c]) > thr){
          if (vv[c] > 0.0f) pos |= (1ull << (jj + c));
          else              neg |= (1ull << (jj + c));
        }
      }
    }
    mpos[j] = pos; mneg[j] = neg;
  }
  // zero previous-spike staging (step -1 = no spikes)
  spk32[tid >> 6][tid & 63] = 0;
  spk32[(tid >> 6) + 4][tid & 63] = 0;
  int r = rbase + row;
  double mem = 0.0, ath = 0.0;
  double bt = (double)beta[r], dc = (double)sfd[r], ic = (double)sfi[r];
  const double* xpr = xp + (size_t)r*CB + k;
  __syncthreads();
  double xv = xpr[0];
  for (int t = 0; t < CT; ++t){
    double xv_next = (t+1 < CT) ? xpr[(size_t)(t+1)*CR*CB] : 0.0;
    int pa[8] = {0,0,0,0,0,0,0,0};
    int na[8] = {0,0,0,0,0,0,0,0};
    #pragma unroll
    for (int j = 0; j < 4; ++j){
      int w = k + 8*j;
      #pragma unroll
      for (int b = 0; b < CB; ++b){
        u64 s = *reinterpret_cast<const u64*>(&spk32[b][2*w]);  // broadcast (same addr per k)
        pa[b] += __popcll(s & mpos[j]);
        na[b] += __popcll(s & mneg[j]);
      }
    }
    int rec[8];
    #pragma unroll
    for (int b = 0; b < CB; ++b) rec[b] = pa[b] - na[b];
    #pragma unroll
    for (int b = 0; b < CB; ++b) rec[b] += __shfl_xor(rec[b], 1);
    #pragma unroll
    for (int b = 0; b < CB; ++b) rec[b] += __shfl_xor(rec[b], 2);
    #pragma unroll
    for (int b = 0; b < CB; ++b) rec[b] += __shfl_xor(rec[b], 4);
    // f64 LIF update (bit-matches numpy-f64 reference trajectory)
    double cur = xv + (double)rec[k];
    mem = bt*mem + cur;
    bool sp = (mem - (1.0 + ath)) > 0.0;
    mem = sp ? 0.0 : mem;
    ath = dc*ath + (sp ? ic : 0.0);
    sbyte[k][row] = sp ? (unsigned char)1 : (unsigned char)0;
    xv = xv_next;
    __syncthreads();
    // publish: plain data stores (wave 0), then one release store of the flag.
    // tid 0..7 are lanes of wave 0 => the release's wave-wide vmcnt drain covers them.
    if (tid < CB){
      const u32* sb = reinterpret_cast<const u32*>(&sbyte[tid][0]);
      u32 word = 0;
      #pragma unroll
      for (int i = 0; i < 8; ++i){
        u32 wv = sb[i];
        word |= ((wv & 1u) | ((wv >> 7) & 2u) | ((wv >> 14) & 4u) | ((wv >> 21) & 8u)) << (4*i);
      }
      acts[((size_t)tid*CT + t)*64 + g] = word;
      pub[(((size_t)(t+1)&1)*CB + tid)*64 + g] = word;
    }
    if (tid == 0)
      __hip_atomic_store(&arrive[(size_t)g*32], (u32)(t+1),
                         __ATOMIC_RELEASE, __HIP_MEMORY_SCOPE_AGENT);
    if (t+1 < CT){
      // wave 0: lane L spins on WG L's flag (monotonic, no reset needed)
      if (tid < 64){
        while (__hip_atomic_load(&arrive[(size_t)tid*32], __ATOMIC_ACQUIRE,
                                 __HIP_MEMORY_SCOPE_AGENT) < (u32)(t+1)) { }
      }
      __syncthreads();
      int par = (t+1) & 1;
      int b0 = tid >> 6, g0 = tid & 63;
      spk32[b0][g0]     = pub[((size_t)par*CB + b0)*64 + g0];
      spk32[b0 + 4][g0] = pub[((size_t)par*CB + b0 + 4)*64 + g0];
      __syncthreads();
    }
  }
}

// ======================= hn = rmsnorm(acts) * rn_w  (spikes are 0/1) =======================
__global__ __launch_bounds__(256) void k_hn(const u32* __restrict__ acts, const float* __restrict__ rn_w,
                                            float* __restrict__ hn){
  int rowbt = blockIdx.x;
  int b = rowbt >> 9, t = rowbt & 511;
  __shared__ u32 wlds[64];
  __shared__ int pc[64];
  __shared__ float sS;
  int tid = threadIdx.x;
  const u32* src = acts + ((size_t)b*CT + t)*64;
  if (tid < 64){ u32 w = src[tid]; wlds[tid] = w; pc[tid] = __popc(w); }
  __syncthreads();
  if (tid == 0){
    int c = 0;
    for (int i = 0; i < 64; ++i) c += pc[i];
    sS = 1.0f / sqrtf((float)c * (1.0f/(float)CR) + 1e-6f);
  }
  __syncthreads();
  float s = sS;
  #pragma unroll
  for (int i = 0; i < 8; ++i){
    int r = tid + 256*i;
    u32 w = wlds[r >> 5];
    float v = ((w >> (r & 31)) & 1u) ? s * rn_w[r] : 0.0f;
    hn[(size_t)rowbt*CR + r] = v;
  }
}

// ======================= generic f32 tiled GEMM, 128x128 tile, 8x8/thread =======================
// EPI: 0 none, 1 +bias->gelu, 2 +bias, 3 silu, 4 +res
struct GemmP {
  const float* A; long lda, Ab, Ah;
  const float* B; long ldb, Bb, Bh;
  float* C;       long ldc, Cb, Ch;
  const float* bias;
  const float* res; long ldr, Rb, Rh;
  float scale;
  int M, N, K, HH;
};

template<int EPI, bool BT>
__global__ __launch_bounds__(256) void k_gemm(GemmP p){
  int bz = blockIdx.z;
  int bb = bz / p.HH, hh = bz - bb*p.HH;
  const float* A = p.A + (size_t)bb*p.Ab + (size_t)hh*p.Ah;
  const float* B = p.B + (size_t)bb*p.Bb + (size_t)hh*p.Bh;
  float* C = p.C + (size_t)bb*p.Cb + (size_t)hh*p.Ch;
  const float* R = p.res ? (p.res + (size_t)bb*p.Rb + (size_t)hh*p.Rh) : (const float*)0;
  int m0 = blockIdx.y*128, n0 = blockIdx.x*128;
  __shared__ float As[16][132];
  __shared__ float Bs[16][132];
  int tid = threadIdx.x;
  int tx = tid & 15, ty = tid >> 4;
  bool a4 = ((p.lda & 3) == 0);
  bool b4 = ((p.ldb & 3) == 0);
  float acc[8][8];
  #pragma unroll
  for (int i = 0; i < 8; ++i)
    #pragma unroll
    for (int j = 0; j < 8; ++j) acc[i][j] = 0.0f;
  for (int k0 = 0; k0 < p.K; k0 += 16){
    // ---- A tile: 128 m x 16 k ----
    {
      int mr = tid >> 2, kc = (tid & 3)*4;
      #pragma unroll
      for (int ps = 0; ps < 2; ++ps){
        int mm = mr + ps*64, gm = m0 + mm, gk = k0 + kc;
        float4 v = make_float4(0.f,0.f,0.f,0.f);
        if (gm < p.M){
          if (a4 && (gk + 3 < p.K)) v = *reinterpret_cast<const float4*>(&A[(size_t)gm*p.lda + gk]);
          else {
            float tv[4];
            #pragma unroll
            for (int c = 0; c < 4; ++c) tv[c] = (gk+c < p.K) ? A[(size_t)gm*p.lda + gk + c] : 0.0f;
            v = make_float4(tv[0],tv[1],tv[2],tv[3]);
          }
        }
        As[kc+0][mm] = v.x; As[kc+1][mm] = v.y; As[kc+2][mm] = v.z; As[kc+3][mm] = v.w;
      }
    }
    // ---- B tile ----
    if (BT){
      int nr = tid >> 2, kc = (tid & 3)*4;
      #pragma unroll
      for (int ps = 0; ps < 2; ++ps){
        int nn = nr + ps*64, gn = n0 + nn, gk = k0 + kc;
        float4 v = make_float4(0.f,0.f,0.f,0.f);
        if (gn < p.N){
          if (b4 && (gk + 3 < p.K)) v = *reinterpret_cast<const float4*>(&B[(size_t)gn*p.ldb + gk]);
          else {
            float tv[4];
            #pragma unroll
            for (int c = 0; c < 4; ++c) tv[c] = (gk+c < p.K) ? B[(size_t)gn*p.ldb + gk + c] : 0.0f;
            v = make_float4(tv[0],tv[1],tv[2],tv[3]);
          }
        }
        Bs[kc+0][nn] = v.x; Bs[kc+1][nn] = v.y; Bs[kc+2][nn] = v.z; Bs[kc+3][nn] = v.w;
      }
    } else {
      int kr = tid >> 5, nc = (tid & 31)*4;
      #pragma unroll
      for (int ps = 0; ps < 2; ++ps){
        int kk = kr + ps*8, gk = k0 + kk, gn = n0 + nc;
        float4 v = make_float4(0.f,0.f,0.f,0.f);
        if (gk < p.K){
          if (b4 && (gn + 3 < p.N)) v = *reinterpret_cast<const float4*>(&B[(size_t)gk*p.ldb + gn]);
          else {
            float tv[4];
            #pragma unroll
            for (int c = 0; c < 4; ++c) tv[c] = (gn+c < p.N) ? B[(size_t)gk*p.ldb + gn + c] : 0.0f;
            v = make_float4(tv[0],tv[1],tv[2],tv[3]);
          }
        }
        *reinterpret_cast<float4*>(&Bs[kk][nc]) = v;
      }
    }
    __syncthreads();
    #pragma unroll
    for (int kk = 0; kk < 16; ++kk){
      float a[8], b[8];
      *reinterpret_cast<float4*>(&a[0]) = *reinterpret_cast<const float4*>(&As[kk][ty*8]);
      *reinterpret_cast<float4*>(&a[4]) = *reinterpret_cast<const float4*>(&As[kk][ty*8+4]);
      *reinterpret_cast<float4*>(&b[0]) = *reinterpret_cast<const float4*>(&Bs[kk][tx*8]);
      *reinterpret_cast<float4*>(&b[4]) = *reinterpret_cast<const float4*>(&Bs[kk][tx*8+4]);
      #pragma unroll
      for (int i = 0; i < 8; ++i)
        #pragma unroll
        for (int j = 0; j < 8; ++j)
          acc[i][j] = fmaf(a[i], b[j], acc[i][j]);
    }
    __syncthreads();
  }
  #pragma unroll
  for (int i = 0; i < 8; ++i){
    int gm = m0 + ty*8 + i;
    if (gm >= p.M) continue;
    #pragma unroll
    for (int j = 0; j < 8; ++j){
      int gn = n0 + tx*8 + j;
      if (gn >= p.N) continue;
      float v = acc[i][j] * p.scale;
      if (EPI == 1){ v += p.bias[gn]; v = 0.5f*v*(1.0f + erff(v*0.7071067811865475f)); }
      else if (EPI == 2){ v += p.bias[gn]; }
      else if (EPI == 3){ v = v / (1.0f + expf(-v)); }
      else if (EPI == 4){ v += R[(size_t)gm*p.ldr + gn]; }
      C[(size_t)gm*p.ldc + gn] = v;
    }
  }
}

template<int EPI, bool BT>
static void run_gemm(const GemmP& p, hipStream_t s, int nbat){
  dim3 grid((p.N + 127)/128, (p.M + 127)/128, nbat), blk(256);
  k_gemm<EPI, BT><<<grid, blk, 0, s>>>(p);
}

// ======================= row softmax (512 cols), in place =======================
__global__ __launch_bounds__(256) void k_softmax(float* __restrict__ sc, long rows){
  long gw = ((long)blockIdx.x*blockDim.x + threadIdx.x) >> 6;
  int lane = threadIdx.x & 63;
  if (gw >= rows) return;
  float* row = sc + gw*512;
  float4 v1 = *reinterpret_cast<const float4*>(row + lane*8);
  float4 v2 = *reinterpret_cast<const float4*>(row + lane*8 + 4);
  float v[8] = {v1.x, v1.y, v1.z, v1.w, v2.x, v2.y, v2.z, v2.w};
  float mx = v[0];
  #pragma unroll
  for (int e = 1; e < 8; ++e) mx = fmaxf(mx, v[e]);
  #pragma unroll
  for (int d = 32; d; d >>= 1) mx = fmaxf(mx, __shfl_xor(mx, d));
  float sum = 0.0f;
  #pragma unroll
  for (int e = 0; e < 8; ++e){ v[e] = expf(v[e] - mx); sum += v[e]; }
  #pragma unroll
  for (int d = 32; d; d >>= 1) sum += __shfl_xor(sum, d);
  float inv = 1.0f / sum;
  float4 o1 = make_float4(v[0]*inv, v[1]*inv, v[2]*inv, v[3]*inv);
  float4 o2 = make_float4(v[4]*inv, v[5]*inv, v[6]*inv, v[7]*inv);
  *reinterpret_cast<float4*>(row + lane*8) = o1;
  *reinterpret_cast<float4*>(row + lane*8 + 4) = o2;
}

// ======================= rmsnorm rows of 512 =======================
__global__ __launch_bounds__(256) void k_rmsnorm(const float* __restrict__ x, const float* __restrict__ w,
                                                 float* __restrict__ o, long rows){
  long gw = ((long)blockIdx.x*blockDim.x + threadIdx.x) >> 6;
  int lane = threadIdx.x & 63;
  if (gw >= rows) return;
  const float* xr = x + gw*512;
  float v[8]; float ss = 0.0f;
  #pragma unroll
  for (int e = 0; e < 8; ++e){ v[e] = xr[lane*8 + e]; ss = fmaf(v[e], v[e], ss); }
  #pragma unroll
  for (int d = 32; d; d >>= 1) ss += __shfl_xor(ss, d);
  float r = 1.0f / sqrtf(ss*(1.0f/512.0f) + 1e-6f);
  float* orow = o + gw*512;
  #pragma unroll
  for (int e = 0; e < 8; ++e) orow[lane*8 + e] = v[e]*r*w[lane*8 + e];
}

// ======================= elementwise g *= u =======================
__global__ __launch_bounds__(256) void k_mul(float* __restrict__ g, const float* __restrict__ u, long n){
  long stride = (long)gridDim.x * blockDim.x;
  for (long i = (long)blockIdx.x*blockDim.x + threadIdx.x; i < n; i += stride) g[i] *= u[i];
}

// ======================= host =======================
extern "C" void kernel_launch(void* const* d_in, const int* in_sizes, int n_in,
                              void* d_out, int out_size, void* d_ws, size_t ws_size,
                              hipStream_t stream){
  (void)n_in; (void)out_size;
  const float* x    = (const float*)d_in[0];
  const float* Wi   = (const float*)d_in[1];
  const float* bi   = (const float*)d_in[2];
  const float* Wr   = (const float*)d_in[3];
  const float* rn_w = (const float*)d_in[4];
  const float* W1   = (const float*)d_in[5];
  const float* b1   = (const float*)d_in[6];
  const float* W2   = (const float*)d_in[7];
  const float* b2   = (const float*)d_in[8];
  const float* anw  = (const float*)d_in[9];
  const float* Wqkv = (const float*)d_in[10];
  const float* Wo   = (const float*)d_in[11];
  const float* fnw  = (const float*)d_in[12];
  const float* Wf1  = (const float*)d_in[13];
  const float* Wf2  = (const float*)d_in[14];
  const float* Wf3  = (const float*)d_in[15];
  const float* beta = (const float*)d_in[16];
  const float* sfi  = (const float*)d_in[17];
  const float* sfd  = (const float*)d_in[18];

  // FFH = int(DIM*2.66) = 1361 (reference comment says 1362 — wrong). Derive from input.
  const long FF = (long)in_sizes[13] / CDIM;

  char* ws = (char*)d_ws;
  size_t cur = 0;
  auto alloc = [&](size_t bytes){ size_t o = cur; cur += (bytes + 255) & ~(size_t)255; return o; };
  size_t oCTRL = alloc(16384);                         // sums @+128, arrive flags @+4096 (8KB)
  size_t oPUB  = alloc((size_t)2*CB*64*4);             // 4 KB spike publication (parity x batch x WG)
  size_t oACTS = alloc((size_t)CB*CT*64*4);            // 1 MB  spike bits
  size_t oXP   = alloc((size_t)CT*CR*CB*8);            // 64 MB f64 xp; reused as scores f32
  size_t oWIQT = alloc((size_t)CDIM*CR*4);
  size_t oW1Q  = alloc((size_t)1024*CR*4);
  size_t oW2Q  = alloc((size_t)512*1024*4);
  size_t oWQKV = alloc((size_t)1536*512*4);
  size_t oWOQ  = alloc((size_t)512*512*4);
  size_t oWF1Q = alloc((size_t)CFFMAX*512*4);
  size_t oWF2Q = alloc((size_t)512*CFFMAX*4);
  size_t oWF3Q = alloc((size_t)CFFMAX*512*4);
  size_t oHN   = alloc((size_t)CM*CR*4);               // hn; reused as g
  size_t oH    = alloc((size_t)CM*1024*4);
  size_t oY    = alloc((size_t)CM*512*4);
  size_t oXA   = alloc((size_t)CM*512*4);              // xa; reused as xf
  size_t oQKV  = alloc((size_t)CM*1536*4);             // qkv; reused as u
  size_t oO    = alloc((size_t)CM*512*4);
  size_t oXR   = alloc((size_t)CM*512*4);
  if (cur > ws_size) return;

  double* sums = (double*)(ws + oCTRL + 128);
  u32* arrive = (u32*)(ws + oCTRL + 4096);
  u32* pub = (u32*)(ws + oPUB);
  u32* uACTS = (u32*)(ws + oACTS);
  double* dXP = (double*)(ws + oXP);
  float* fSC  = (float*)(ws + oXP);
  float* fWIQT = (float*)(ws + oWIQT);
  float* fW1Q = (float*)(ws + oW1Q);
  float* fW2Q = (float*)(ws + oW2Q);
  float* fWQKV = (float*)(ws + oWQKV);
  float* fWOQ = (float*)(ws + oWOQ);
  float* fWF1Q = (float*)(ws + oWF1Q);
  float* fWF2Q = (float*)(ws + oWF2Q);
  float* fWF3Q = (float*)(ws + oWF3Q);
  float* fHN = (float*)(ws + oHN);
  float* fG  = (float*)(ws + oHN);
  float* fH  = (float*)(ws + oH);
  float* fY  = (float*)(ws + oY);
  float* fXA = (float*)(ws + oXA);
  float* fQKV = (float*)(ws + oQKV);
  float* fU  = (float*)(ws + oQKV);
  float* fO  = (float*)(ws + oO);
  float* fXR = (float*)(ws + oXR);
  float* out = (float*)d_out;

  dim3 b256(256);
  hipMemsetAsync(ws + oCTRL, 0, 16384, stream);

  k_abssum<<<512, b256, 0, stream>>>(Wi,  (long)CR*CDIM,  sums, 0);
  k_abssum<<<512, b256, 0, stream>>>(Wr,  (long)CR*CR,    sums, 1);
  k_abssum<<<512, b256, 0, stream>>>(W1,  (long)1024*CR,  sums, 2);
  k_abssum<<<512, b256, 0, stream>>>(W2,  (long)512*1024, sums, 3);
  k_abssum<<<512, b256, 0, stream>>>(Wqkv,(long)1536*512, sums, 4);
  k_abssum<<<512, b256, 0, stream>>>(Wo,  (long)512*512,  sums, 5);
  k_abssum<<<512, b256, 0, stream>>>(Wf1, FF*512,         sums, 6);
  k_abssum<<<512, b256, 0, stream>>>(Wf2, 512*FF,         sums, 7);
  k_abssum<<<512, b256, 0, stream>>>(Wf3, FF*512,         sums, 8);

  k_decodeT<<<1024, b256, 0, stream>>>(Wi, fWIQT, CR, CDIM, sums, 0, 1.0/((double)CR*CDIM));
  k_decode<<<1024, b256, 0, stream>>>(W1,  fW1Q, (long)1024*CR,  sums, 2, 1.0/((double)1024*CR));
  k_decode<<<1024, b256, 0, stream>>>(W2,  fW2Q, (long)512*1024, sums, 3, 1.0/((double)512*1024));
  k_decode<<<1024, b256, 0, stream>>>(Wqkv,fWQKV,(long)1536*512, sums, 4, 1.0/((double)1536*512));
  k_decode<<<1024, b256, 0, stream>>>(Wo,  fWOQ, (long)512*512,  sums, 5, 1.0/((double)512*512));
  k_decode<<<1024, b256, 0, stream>>>(Wf1, fWF1Q, FF*512,        sums, 6, 1.0/((double)FF*512));
  k_decode<<<1024, b256, 0, stream>>>(Wf2, fWF2Q, 512*FF,        sums, 7, 1.0/((double)FF*512));
  k_decode<<<1024, b256, 0, stream>>>(Wf3, fWF3Q, FF*512,        sums, 8, 1.0/((double)FF*512));

  k_xp<<<dim3(CR/256, CT), b256, 0, stream>>>(x, fWIQT, bi, dXP);
  k_scan<<<SCAN_WGS, b256, 0, stream>>>(Wr, dXP, beta, sfi, sfd, sums, uACTS, pub, arrive);
  k_hn<<<CM, b256, 0, stream>>>(uACTS, rn_w, fHN);

  // h = gelu(hn @ W1q^T + b1)
  { GemmP p{fHN, CR,0,0,  fW1Q, CR,0,0,  fH, 1024,0,0,  b1,  (const float*)0,0,0,0, 1.0f, CM,1024,CR,1};
    run_gemm<1,true>(p, stream, 1); }
  // y = h @ W2q^T + b2
  { GemmP p{fH, 1024,0,0, fW2Q, 1024,0,0, fY, 512,0,0,  b2,  (const float*)0,0,0,0, 1.0f, CM,512,1024,1};
    run_gemm<2,true>(p, stream, 1); }
  k_rmsnorm<<<CM/4, b256, 0, stream>>>(fY, anw, fXA, CM);
  // qkv = xa @ Wqkv^T
  { GemmP p{fXA, 512,0,0, fWQKV, 512,0,0, fQKV, 1536,0,0, (const float*)0, (const float*)0,0,0,0, 1.0f, CM,1536,512,1};
    run_gemm<0,true>(p, stream, 1); }
  // scores[b,h] = q @ k^T * 0.125
  { GemmP p{fQKV,       1536, 786432, 64,
            fQKV + 512, 1536, 786432, 64,
            fSC,        512,  2097152, 262144,
            (const float*)0, (const float*)0,0,0,0, 0.125f, 512,512,64,CH};
    run_gemm<0,true>(p, stream, CB*CH); }
  k_softmax<<<(long)CB*CH*512/4, b256, 0, stream>>>(fSC, (long)CB*CH*512);
  // o[b,h] = attn @ v
  { GemmP p{fSC,         512,  2097152, 262144,
            fQKV + 1024, 1536, 786432,  64,
            fO,          512,  262144,  64,
            (const float*)0, (const float*)0,0,0,0, 1.0f, 512,64,512,CH};
    run_gemm<0,false>(p, stream, CB*CH); }
  // x_res = y + o @ Wo^T
  { GemmP p{fO, 512,0,0, fWOQ, 512,0,0, fXR, 512,0,0, (const float*)0, fY, 512,0,0, 1.0f, CM,512,512,1};
    run_gemm<4,true>(p, stream, 1); }
  k_rmsnorm<<<CM/4, b256, 0, stream>>>(fXR, fnw, fXA, CM);
  // g = silu(xf @ Wf1^T)
  { GemmP p{fXA, 512,0,0, fWF1Q, 512,0,0, fG, FF,0,0, (const float*)0, (const float*)0,0,0,0, 1.0f, CM,(int)FF,512,1};
    run_gemm<3,true>(p, stream, 1); }
  // u = xf @ Wf3^T
  { GemmP p{fXA, 512,0,0, fWF3Q, 512,0,0, fU, FF,0,0, (const float*)0, (const float*)0,0,0,0, 1.0f, CM,(int)FF,512,1};
    run_gemm<0,true>(p, stream, 1); }
  k_mul<<<2048, b256, 0, stream>>>(fG, fU, (long)CM*FF);
  // out = x_res + (g*u) @ Wf2^T
  { GemmP p{fG, FF,0,0, fWF2Q, FF,0,0, out, 512,0,0, (const float*)0, fXR, 512,0,0, 1.0f, CM,512,(int)FF,1};
    run_gemm<4,true>(p, stream, 1); }
}

// Round 8
// 3775.858 us; speedup vs baseline: 1.9307x; 1.2323x over previous
//
#include <hip/hip_runtime.h>
#include <stdint.h>

typedef unsigned int u32;
typedef unsigned long long u64;

#define CB 8
#define CT 512
#define CDIM 512
#define CR 2048
#define CH 8
#define CHD 64
#define CFFMAX 1368        // upper bound for workspace sizing only; real FF from in_sizes
#define CM 4096            // B*T

// ======================= |w| sums (for ternary thresholds) =======================
__global__ __launch_bounds__(256) void k_abssum(const float* __restrict__ w, long n,
                                                double* __restrict__ sums, int idx){
  double s = 0.0;
  long stride = (long)gridDim.x * blockDim.x;
  for (long i = (long)blockIdx.x*blockDim.x + threadIdx.x; i < n; i += stride)
    s += (double)fabsf(w[i]);
  #pragma unroll
  for (int d = 32; d; d >>= 1) s += __shfl_down(s, d);
  __shared__ double ps[4];
  int lane = threadIdx.x & 63, wv = threadIdx.x >> 6;
  if (lane == 0) ps[wv] = s;
  __syncthreads();
  if (threadIdx.x == 0) atomicAdd(&sums[idx], ps[0]+ps[1]+ps[2]+ps[3]);
}

// ======================= ternary decode to f32 {-1,0,1} =======================
__global__ __launch_bounds__(256) void k_decode(const float* __restrict__ w, float* __restrict__ q,
                                                long n, const double* __restrict__ sums, int idx, double invN){
  double thr = 0.7 * (sums[idx] * invN);
  long stride = (long)gridDim.x * blockDim.x;
  for (long i = (long)blockIdx.x*blockDim.x + threadIdx.x; i < n; i += stride){
    float v = w[i];
    q[i] = (fabs((double)v) > thr) ? (v > 0.0f ? 1.0f : -1.0f) : 0.0f;
  }
}

// decode + transpose: w[rows][cols] -> qT[cols][rows]   (used for Wi)
__global__ __launch_bounds__(256) void k_decodeT(const float* __restrict__ w, float* __restrict__ qT,
                                                 long rows, long cols, const double* __restrict__ sums,
                                                 int idx, double invN){
  double thr = 0.7 * (sums[idx] * invN);
  long n = rows * cols;
  long stride = (long)gridDim.x * blockDim.x;
  for (long i = (long)blockIdx.x*blockDim.x + threadIdx.x; i < n; i += stride){
    long r = i / cols, d = i - r*cols;
    float v = w[i];
    float o = (fabs((double)v) > thr) ? (v > 0.0f ? 1.0f : -1.0f) : 0.0f;
    qT[d*rows + r] = o;
  }
}

// ======================= Wr -> ternary bitmasks mb[r][w][2] (pos,neg) =======================
__global__ __launch_bounds__(256) void k_maskbuild(const float* __restrict__ Wr,
                                                   const double* __restrict__ sums,
                                                   u64* __restrict__ mb){
  int n = blockIdx.x*256 + threadIdx.x;     // 0..65535
  int r = n >> 5, w = n & 31;
  double thr = 0.7 * (sums[1] * (1.0/((double)CR*(double)CR)));
  const float* src = Wr + (size_t)r*CR + w*64;
  u64 pos = 0, neg = 0;
  for (int j = 0; j < 64; j += 4){
    float4 v4 = *reinterpret_cast<const float4*>(src + j);
    float vv[4] = {v4.x, v4.y, v4.z, v4.w};
    #pragma unroll
    for (int c = 0; c < 4; ++c){
      if (fabs((double)vv[c]) > thr){
        if (vv[c] > 0.0f) pos |= (1ull << (j + c));
        else              neg |= (1ull << (j + c));
      }
    }
  }
  mb[((size_t)r*32 + w)*2 + 0] = pos;
  mb[((size_t)r*32 + w)*2 + 1] = neg;
}

// ======================= xp = x @ ternary(Wi)^T + bi  (f64 exact), layout xp[b][t][r] ==========
__global__ __launch_bounds__(256) void k_xp(const float* __restrict__ x, const float* __restrict__ wiqT,
                                            const float* __restrict__ bi, double* __restrict__ xp){
  int t = blockIdx.y;
  int r = blockIdx.x*256 + threadIdx.x;
  __shared__ double xs[CB][CDIM];          // 32 KB
  for (int i = threadIdx.x; i < CB*CDIM; i += 256){
    int b = i >> 9, d = i & 511;
    xs[b][d] = (double)x[((size_t)b*CT + t)*CDIM + d];
  }
  __syncthreads();
  double acc[CB];
  #pragma unroll
  for (int b = 0; b < CB; ++b) acc[b] = 0.0;
  for (int d = 0; d < CDIM; ++d){
    double wd = (double)wiqT[(size_t)d*CR + r];
    #pragma unroll
    for (int b = 0; b < CB; ++b) acc[b] = fma(wd, xs[b][d], acc[b]);
  }
  double bd = (double)bi[r];
  #pragma unroll
  for (int b = 0; b < CB; ++b)
    xp[((size_t)b*CT + t)*CR + r] = acc[b] + bd;
}

// ======================= LIF reservoir scan — batch-independent groups =======================
// 64 WGs = 8 groups (one per batch) x 8 WGs. Group x = blocks {x, x+8,...} (XCD-affine under
// round-robin dispatch; correctness placement-independent). WG (x,wgin) owns neurons
// [wgin*256, wgin*256+256) for batch x; 1 row/thread, full-row masks in 128 VGPRs.
// Per-step sync WITHIN the 8-WG group only: 64-B packet/WG = 4 wave-ballots + stamp (written
// last, agent-release), parity double-buffered. Lanes 0..7 of wave 0 poll the 8 packets
// (stamp>=t+1), stage 2048 spike bits into LDS. Same parity-safety proof as rounds 2-5:
// a slot is overwritten (stamp t+1) only after every group member published stamp t, which
// happens only after that member finished reading the slot's stamp t-1 data.
__global__ __launch_bounds__(256, 1) void k_scan(const u64* __restrict__ mb,
                                                 const double* __restrict__ xp,   // [b][t][r]
                                                 const float* __restrict__ beta,
                                                 const float* __restrict__ sfi,
                                                 const float* __restrict__ sfd,
                                                 u32* __restrict__ acts,
                                                 u64* __restrict__ pub){          // [2][8][8][8] u64
  __shared__ u64 spk[32];     // full 2048-bit spike vector of this batch (prev step)
  __shared__ u64 bal[4];      // this WG's wave ballots
  int tid = threadIdx.x;
  int blk = blockIdx.x;
  int x = blk & 7;            // batch / group
  int wgin = blk >> 3;        // 0..7 within group
  int r = wgin*256 + tid;     // global neuron row
  // masks in registers: 32 x (pos,neg)
  u64 mpos[32], mneg[32];
  const u64* m = mb + (size_t)r*64;
  #pragma unroll
  for (int w = 0; w < 32; ++w){ mpos[w] = m[2*w]; mneg[w] = m[2*w+1]; }
  if (tid < 32) spk[tid] = 0;
  double mem = 0.0, ath = 0.0;
  double bt = (double)beta[r], dc = (double)sfd[r], ic = (double)sfi[r];
  const double* xpr = xp + ((size_t)x*CT)*CR + r;
  __syncthreads();
  double xv = xpr[0];
  for (int t = 0; t < CT; ++t){
    double xv_next = (t+1 < CT) ? xpr[(size_t)(t+1)*CR] : 0.0;
    int pa = 0, na = 0;
    #pragma unroll
    for (int w = 0; w < 32; ++w){
      u64 s = spk[w];                       // broadcast read
      pa += __popcll(s & mpos[w]);
      na += __popcll(s & mneg[w]);
    }
    // f64 LIF update — identical op sequence to prior rounds => bit-identical trajectory
    double cur = xv + (double)(pa - na);
    mem = bt*mem + cur;
    bool sp = (mem - (1.0 + ath)) > 0.0;
    mem = sp ? 0.0 : mem;
    ath = dc*ath + (sp ? ic : 0.0);
    u64 ball = __ballot(sp);
    if ((tid & 63) == 0) bal[tid >> 6] = ball;
    xv = xv_next;
    __syncthreads();
    // acts words for k_hn: u32 word (wgin*8 + tid) covers rows [wgin*256 + tid*32, +32)
    if (tid < 8){
      u64 b64 = bal[tid >> 1];
      u32 wrd = (u32)(b64 >> ((tid & 1)*32));
      acts[((size_t)x*CT + t)*64 + wgin*8 + tid] = wrd;
    }
    if (t+1 < CT){
      int par = (t+1) & 1;
      if (tid == 0){
        u64* mypkt = pub + (((size_t)par*8 + x)*8 + wgin)*8;
        mypkt[0] = bal[0]; mypkt[1] = bal[1]; mypkt[2] = bal[2]; mypkt[3] = bal[3];
        __hip_atomic_store(&mypkt[4], (u64)(u32)(t+1),
                           __ATOMIC_RELEASE, __HIP_MEMORY_SCOPE_AGENT);
      }
      if (tid < 8){
        u64* pk = pub + (((size_t)par*8 + x)*8 + tid)*8;
        while ((u32)__hip_atomic_load(&pk[4], __ATOMIC_ACQUIRE,
                                      __HIP_MEMORY_SCOPE_AGENT) < (u32)(t+1)) { }
        spk[tid*4 + 0] = pk[0];
        spk[tid*4 + 1] = pk[1];
        spk[tid*4 + 2] = pk[2];
        spk[tid*4 + 3] = pk[3];
      }
      __syncthreads();
    }
  }
}

// ======================= hn = rmsnorm(acts) * rn_w  (spikes are 0/1) =======================
__global__ __launch_bounds__(256) void k_hn(const u32* __restrict__ acts, const float* __restrict__ rn_w,
                                            float* __restrict__ hn){
  int rowbt = blockIdx.x;
  int b = rowbt >> 9, t = rowbt & 511;
  __shared__ u32 wlds[64];
  __shared__ int pc[64];
  __shared__ float sS;
  int tid = threadIdx.x;
  const u32* src = acts + ((size_t)b*CT + t)*64;
  if (tid < 64){ u32 w = src[tid]; wlds[tid] = w; pc[tid] = __popc(w); }
  __syncthreads();
  if (tid == 0){
    int c = 0;
    for (int i = 0; i < 64; ++i) c += pc[i];
    sS = 1.0f / sqrtf((float)c * (1.0f/(float)CR) + 1e-6f);
  }
  __syncthreads();
  float s = sS;
  #pragma unroll
  for (int i = 0; i < 8; ++i){
    int r = tid + 256*i;
    u32 w = wlds[r >> 5];
    float v = ((w >> (r & 31)) & 1u) ? s * rn_w[r] : 0.0f;
    hn[(size_t)rowbt*CR + r] = v;
  }
}

// ======================= generic f32 tiled GEMM, 128x128 tile, 8x8/thread =======================
// EPI: 0 none, 1 +bias->gelu, 2 +bias, 3 silu, 4 +res
struct GemmP {
  const float* A; long lda, Ab, Ah;
  const float* B; long ldb, Bb, Bh;
  float* C;       long ldc, Cb, Ch;
  const float* bias;
  const float* res; long ldr, Rb, Rh;
  float scale;
  int M, N, K, HH;
};

template<int EPI, bool BT>
__global__ __launch_bounds__(256) void k_gemm(GemmP p){
  int bz = blockIdx.z;
  int bb = bz / p.HH, hh = bz - bb*p.HH;
  const float* A = p.A + (size_t)bb*p.Ab + (size_t)hh*p.Ah;
  const float* B = p.B + (size_t)bb*p.Bb + (size_t)hh*p.Bh;
  float* C = p.C + (size_t)bb*p.Cb + (size_t)hh*p.Ch;
  const float* R = p.res ? (p.res + (size_t)bb*p.Rb + (size_t)hh*p.Rh) : (const float*)0;
  int m0 = blockIdx.y*128, n0 = blockIdx.x*128;
  __shared__ float As[16][132];
  __shared__ float Bs[16][132];
  int tid = threadIdx.x;
  int tx = tid & 15, ty = tid >> 4;
  bool a4 = ((p.lda & 3) == 0);
  bool b4 = ((p.ldb & 3) == 0);
  float acc[8][8];
  #pragma unroll
  for (int i = 0; i < 8; ++i)
    #pragma unroll
    for (int j = 0; j < 8; ++j) acc[i][j] = 0.0f;
  for (int k0 = 0; k0 < p.K; k0 += 16){
    {
      int mr = tid >> 2, kc = (tid & 3)*4;
      #pragma unroll
      for (int ps = 0; ps < 2; ++ps){
        int mm = mr + ps*64, gm = m0 + mm, gk = k0 + kc;
        float4 v = make_float4(0.f,0.f,0.f,0.f);
        if (gm < p.M){
          if (a4 && (gk + 3 < p.K)) v = *reinterpret_cast<const float4*>(&A[(size_t)gm*p.lda + gk]);
          else {
            float tv[4];
            #pragma unroll
            for (int c = 0; c < 4; ++c) tv[c] = (gk+c < p.K) ? A[(size_t)gm*p.lda + gk + c] : 0.0f;
            v = make_float4(tv[0],tv[1],tv[2],tv[3]);
          }
        }
        As[kc+0][mm] = v.x; As[kc+1][mm] = v.y; As[kc+2][mm] = v.z; As[kc+3][mm] = v.w;
      }
    }
    if (BT){
      int nr = tid >> 2, kc = (tid & 3)*4;
      #pragma unroll
      for (int ps = 0; ps < 2; ++ps){
        int nn = nr + ps*64, gn = n0 + nn, gk = k0 + kc;
        float4 v = make_float4(0.f,0.f,0.f,0.f);
        if (gn < p.N){
          if (b4 && (gk + 3 < p.K)) v = *reinterpret_cast<const float4*>(&B[(size_t)gn*p.ldb + gk]);
          else {
            float tv[4];
            #pragma unroll
            for (int c = 0; c < 4; ++c) tv[c] = (gk+c < p.K) ? B[(size_t)gn*p.ldb + gk + c] : 0.0f;
            v = make_float4(tv[0],tv[1],tv[2],tv[3]);
          }
        }
        Bs[kc+0][nn] = v.x; Bs[kc+1][nn] = v.y; Bs[kc+2][nn] = v.z; Bs[kc+3][nn] = v.w;
      }
    } else {
      int kr = tid >> 5, nc = (tid & 31)*4;
      #pragma unroll
      for (int ps = 0; ps < 2; ++ps){
        int kk = kr + ps*8, gk = k0 + kk, gn = n0 + nc;
        float4 v = make_float4(0.f,0.f,0.f,0.f);
        if (gk < p.K){
          if (b4 && (gn + 3 < p.N)) v = *reinterpret_cast<const float4*>(&B[(size_t)gk*p.ldb + gn]);
          else {
            float tv[4];
            #pragma unroll
            for (int c = 0; c < 4; ++c) tv[c] = (gn+c < p.N) ? B[(size_t)gk*p.ldb + gn + c] : 0.0f;
            v = make_float4(tv[0],tv[1],tv[2],tv[3]);
          }
        }
        *reinterpret_cast<float4*>(&Bs[kk][nc]) = v;
      }
    }
    __syncthreads();
    #pragma unroll
    for (int kk = 0; kk < 16; ++kk){
      float a[8], b[8];
      *reinterpret_cast<float4*>(&a[0]) = *reinterpret_cast<const float4*>(&As[kk][ty*8]);
      *reinterpret_cast<float4*>(&a[4]) = *reinterpret_cast<const float4*>(&As[kk][ty*8+4]);
      *reinterpret_cast<float4*>(&b[0]) = *reinterpret_cast<const float4*>(&Bs[kk][tx*8]);
      *reinterpret_cast<float4*>(&b[4]) = *reinterpret_cast<const float4*>(&Bs[kk][tx*8+4]);
      #pragma unroll
      for (int i = 0; i < 8; ++i)
        #pragma unroll
        for (int j = 0; j < 8; ++j)
          acc[i][j] = fmaf(a[i], b[j], acc[i][j]);
    }
    __syncthreads();
  }
  #pragma unroll
  for (int i = 0; i < 8; ++i){
    int gm = m0 + ty*8 + i;
    if (gm >= p.M) continue;
    #pragma unroll
    for (int j = 0; j < 8; ++j){
      int gn = n0 + tx*8 + j;
      if (gn >= p.N) continue;
      float v = acc[i][j] * p.scale;
      if (EPI == 1){ v += p.bias[gn]; v = 0.5f*v*(1.0f + erff(v*0.7071067811865475f)); }
      else if (EPI == 2){ v += p.bias[gn]; }
      else if (EPI == 3){ v = v / (1.0f + expf(-v)); }
      else if (EPI == 4){ v += R[(size_t)gm*p.ldr + gn]; }
      C[(size_t)gm*p.ldc + gn] = v;
    }
  }
}

template<int EPI, bool BT>
static void run_gemm(const GemmP& p, hipStream_t s, int nbat){
  dim3 grid((p.N + 127)/128, (p.M + 127)/128, nbat), blk(256);
  k_gemm<EPI, BT><<<grid, blk, 0, s>>>(p);
}

// ======================= row softmax (512 cols), in place =======================
__global__ __launch_bounds__(256) void k_softmax(float* __restrict__ sc, long rows){
  long gw = ((long)blockIdx.x*blockDim.x + threadIdx.x) >> 6;
  int lane = threadIdx.x & 63;
  if (gw >= rows) return;
  float* row = sc + gw*512;
  float4 v1 = *reinterpret_cast<const float4*>(row + lane*8);
  float4 v2 = *reinterpret_cast<const float4*>(row + lane*8 + 4);
  float v[8] = {v1.x, v1.y, v1.z, v1.w, v2.x, v2.y, v2.z, v2.w};
  float mx = v[0];
  #pragma unroll
  for (int e = 1; e < 8; ++e) mx = fmaxf(mx, v[e]);
  #pragma unroll
  for (int d = 32; d; d >>= 1) mx = fmaxf(mx, __shfl_xor(mx, d));
  float sum = 0.0f;
  #pragma unroll
  for (int e = 0; e < 8; ++e){ v[e] = expf(v[e] - mx); sum += v[e]; }
  #pragma unroll
  for (int d = 32; d; d >>= 1) sum += __shfl_xor(sum, d);
  float inv = 1.0f / sum;
  float4 o1 = make_float4(v[0]*inv, v[1]*inv, v[2]*inv, v[3]*inv);
  float4 o2 = make_float4(v[4]*inv, v[5]*inv, v[6]*inv, v[7]*inv);
  *reinterpret_cast<float4*>(row + lane*8) = o1;
  *reinterpret_cast<float4*>(row + lane*8 + 4) = o2;
}

// ======================= rmsnorm rows of 512 =======================
__global__ __launch_bounds__(256) void k_rmsnorm(const float* __restrict__ x, const float* __restrict__ w,
                                                 float* __restrict__ o, long rows){
  long gw = ((long)blockIdx.x*blockDim.x + threadIdx.x) >> 6;
  int lane = threadIdx.x & 63;
  if (gw >= rows) return;
  const float* xr = x + gw*512;
  float v[8]; float ss = 0.0f;
  #pragma unroll
  for (int e = 0; e < 8; ++e){ v[e] = xr[lane*8 + e]; ss = fmaf(v[e], v[e], ss); }
  #pragma unroll
  for (int d = 32; d; d >>= 1) ss += __shfl_xor(ss, d);
  float r = 1.0f / sqrtf(ss*(1.0f/512.0f) + 1e-6f);
  float* orow = o + gw*512;
  #pragma unroll
  for (int e = 0; e < 8; ++e) orow[lane*8 + e] = v[e]*r*w[lane*8 + e];
}

// ======================= elementwise g *= u =======================
__global__ __launch_bounds__(256) void k_mul(float* __restrict__ g, const float* __restrict__ u, long n){
  long stride = (long)gridDim.x * blockDim.x;
  for (long i = (long)blockIdx.x*blockDim.x + threadIdx.x; i < n; i += stride) g[i] *= u[i];
}

// ======================= host =======================
extern "C" void kernel_launch(void* const* d_in, const int* in_sizes, int n_in,
                              void* d_out, int out_size, void* d_ws, size_t ws_size,
                              hipStream_t stream){
  (void)n_in; (void)out_size;
  const float* x    = (const float*)d_in[0];
  const float* Wi   = (const float*)d_in[1];
  const float* bi   = (const float*)d_in[2];
  const float* Wr   = (const float*)d_in[3];
  const float* rn_w = (const float*)d_in[4];
  const float* W1   = (const float*)d_in[5];
  const float* b1   = (const float*)d_in[6];
  const float* W2   = (const float*)d_in[7];
  const float* b2   = (const float*)d_in[8];
  const float* anw  = (const float*)d_in[9];
  const float* Wqkv = (const float*)d_in[10];
  const float* Wo   = (const float*)d_in[11];
  const float* fnw  = (const float*)d_in[12];
  const float* Wf1  = (const float*)d_in[13];
  const float* Wf2  = (const float*)d_in[14];
  const float* Wf3  = (const float*)d_in[15];
  const float* beta = (const float*)d_in[16];
  const float* sfi  = (const float*)d_in[17];
  const float* sfd  = (const float*)d_in[18];

  // FFH = int(DIM*2.66) = 1361 (reference comment says 1362 — wrong). Derive from input.
  const long FF = (long)in_sizes[13] / CDIM;

  char* ws = (char*)d_ws;
  size_t cur = 0;
  auto alloc = [&](size_t bytes){ size_t o = cur; cur += (bytes + 255) & ~(size_t)255; return o; };
  size_t oCTRL = alloc(16384);                         // sums @+128, pub packets @+8192 (8 KB)
  size_t oMB   = alloc((size_t)CR*32*2*8);             // 1 MB ternary Wr bitmasks
  size_t oACTS = alloc((size_t)CB*CT*64*4);            // 1 MB spike bits
  size_t oXP   = alloc((size_t)CT*CR*CB*8);            // 64 MB f64 xp [b][t][r]; reused as scores f32
  size_t oWIQT = alloc((size_t)CDIM*CR*4);
  size_t oW1Q  = alloc((size_t)1024*CR*4);
  size_t oW2Q  = alloc((size_t)512*1024*4);
  size_t oWQKV = alloc((size_t)1536*512*4);
  size_t oWOQ  = alloc((size_t)512*512*4);
  size_t oWF1Q = alloc((size_t)CFFMAX*512*4);
  size_t oWF2Q = alloc((size_t)512*CFFMAX*4);
  size_t oWF3Q = alloc((size_t)CFFMAX*512*4);
  size_t oHN   = alloc((size_t)CM*CR*4);               // hn; reused as g
  size_t oH    = alloc((size_t)CM*1024*4);
  size_t oY    = alloc((size_t)CM*512*4);
  size_t oXA   = alloc((size_t)CM*512*4);              // xa; reused as xf
  size_t oQKV  = alloc((size_t)CM*1536*4);             // qkv; reused as u
  size_t oO    = alloc((size_t)CM*512*4);
  size_t oXR   = alloc((size_t)CM*512*4);
  if (cur > ws_size) return;

  double* sums = (double*)(ws + oCTRL + 128);
  u64* pub = (u64*)(ws + oCTRL + 8192);
  u64* uMB = (u64*)(ws + oMB);
  u32* uACTS = (u32*)(ws + oACTS);
  double* dXP = (double*)(ws + oXP);
  float* fSC  = (float*)(ws + oXP);
  float* fWIQT = (float*)(ws + oWIQT);
  float* fW1Q = (float*)(ws + oW1Q);
  float* fW2Q = (float*)(ws + oW2Q);
  float* fWQKV = (float*)(ws + oWQKV);
  float* fWOQ = (float*)(ws + oWOQ);
  float* fWF1Q = (float*)(ws + oWF1Q);
  float* fWF2Q = (float*)(ws + oWF2Q);
  float* fWF3Q = (float*)(ws + oWF3Q);
  float* fHN = (float*)(ws + oHN);
  float* fG  = (float*)(ws + oHN);
  float* fH  = (float*)(ws + oH);
  float* fY  = (float*)(ws + oY);
  float* fXA = (float*)(ws + oXA);
  float* fQKV = (float*)(ws + oQKV);
  float* fU  = (float*)(ws + oQKV);
  float* fO  = (float*)(ws + oO);
  float* fXR = (float*)(ws + oXR);
  float* out = (float*)d_out;

  dim3 b256(256);
  hipMemsetAsync(ws + oCTRL, 0, 16384, stream);

  k_abssum<<<512, b256, 0, stream>>>(Wi,  (long)CR*CDIM,  sums, 0);
  k_abssum<<<512, b256, 0, stream>>>(Wr,  (long)CR*CR,    sums, 1);
  k_abssum<<<512, b256, 0, stream>>>(W1,  (long)1024*CR,  sums, 2);
  k_abssum<<<512, b256, 0, stream>>>(W2,  (long)512*1024, sums, 3);
  k_abssum<<<512, b256, 0, stream>>>(Wqkv,(long)1536*512, sums, 4);
  k_abssum<<<512, b256, 0, stream>>>(Wo,  (long)512*512,  sums, 5);
  k_abssum<<<512, b256, 0, stream>>>(Wf1, FF*512,         sums, 6);
  k_abssum<<<512, b256, 0, stream>>>(Wf2, 512*FF,         sums, 7);
  k_abssum<<<512, b256, 0, stream>>>(Wf3, FF*512,         sums, 8);

  k_maskbuild<<<256, b256, 0, stream>>>(Wr, sums, uMB);
  k_decodeT<<<1024, b256, 0, stream>>>(Wi, fWIQT, CR, CDIM, sums, 0, 1.0/((double)CR*CDIM));
  k_decode<<<1024, b256, 0, stream>>>(W1,  fW1Q, (long)1024*CR,  sums, 2, 1.0/((double)1024*CR));
  k_decode<<<1024, b256, 0, stream>>>(W2,  fW2Q, (long)512*1024, sums, 3, 1.0/((double)512*1024));
  k_decode<<<1024, b256, 0, stream>>>(Wqkv,fWQKV,(long)1536*512, sums, 4, 1.0/((double)1536*512));
  k_decode<<<1024, b256, 0, stream>>>(Wo,  fWOQ, (long)512*512,  sums, 5, 1.0/((double)512*512));
  k_decode<<<1024, b256, 0, stream>>>(Wf1, fWF1Q, FF*512,        sums, 6, 1.0/((double)FF*512));
  k_decode<<<1024, b256, 0, stream>>>(Wf2, fWF2Q, 512*FF,        sums, 7, 1.0/((double)FF*512));
  k_decode<<<1024, b256, 0, stream>>>(Wf3, fWF3Q, FF*512,        sums, 8, 1.0/((double)FF*512));

  k_xp<<<dim3(CR/256, CT), b256, 0, stream>>>(x, fWIQT, bi, dXP);
  k_scan<<<64, b256, 0, stream>>>(uMB, dXP, beta, sfi, sfd, uACTS, pub);
  k_hn<<<CM, b256, 0, stream>>>(uACTS, rn_w, fHN);

  // h = gelu(hn @ W1q^T + b1)
  { GemmP p{fHN, CR,0,0,  fW1Q, CR,0,0,  fH, 1024,0,0,  b1,  (const float*)0,0,0,0, 1.0f, CM,1024,CR,1};
    run_gemm<1,true>(p, stream, 1); }
  // y = h @ W2q^T + b2
  { GemmP p{fH, 1024,0,0, fW2Q, 1024,0,0, fY, 512,0,0,  b2,  (const float*)0,0,0,0, 1.0f, CM,512,1024,1};
    run_gemm<2,true>(p, stream, 1); }
  k_rmsnorm<<<CM/4, b256, 0, stream>>>(fY, anw, fXA, CM);
  // qkv = xa @ Wqkv^T
  { GemmP p{fXA, 512,0,0, fWQKV, 512,0,0, fQKV, 1536,0,0, (const float*)0, (const float*)0,0,0,0, 1.0f, CM,1536,512,1};
    run_gemm<0,true>(p, stream, 1); }
  // scores[b,h] = q @ k^T * 0.125
  { GemmP p{fQKV,       1536, 786432, 64,
            fQKV + 512, 1536, 786432, 64,
            fSC,        512,  2097152, 262144,
            (const float*)0, (const float*)0,0,0,0, 0.125f, 512,512,64,CH};
    run_gemm<0,true>(p, stream, CB*CH); }
  k_softmax<<<(long)CB*CH*512/4, b256, 0, stream>>>(fSC, (long)CB*CH*512);
  // o[b,h] = attn @ v
  { GemmP p{fSC,         512,  2097152, 262144,
            fQKV + 1024, 1536, 786432,  64,
            fO,          512,  262144,  64,
            (const float*)0, (const float*)0,0,0,0, 1.0f, 512,64,512,CH};
    run_gemm<0,false>(p, stream, CB*CH); }
  // x_res = y + o @ Wo^T
  { GemmP p{fO, 512,0,0, fWOQ, 512,0,0, fXR, 512,0,0, (const float*)0, fY, 512,0,0, 1.0f, CM,512,512,1};
    run_gemm<4,true>(p, stream, 1); }
  k_rmsnorm<<<CM/4, b256, 0, stream>>>(fXR, fnw, fXA, CM);
  // g = silu(xf @ Wf1^T)
  { GemmP p{fXA, 512,0,0, fWF1Q, 512,0,0, fG, FF,0,0, (const float*)0, (const float*)0,0,0,0, 1.0f, CM,(int)FF,512,1};
    run_gemm<3,true>(p, stream, 1); }
  // u = xf @ Wf3^T
  { GemmP p{fXA, 512,0,0, fWF3Q, 512,0,0, fU, FF,0,0, (const float*)0, (const float*)0,0,0,0, 1.0f, CM,(int)FF,512,1};
    run_gemm<0,true>(p, stream, 1); }
  k_mul<<<2048, b256, 0, stream>>>(fG, fU, (long)CM*FF);
  // out = x_res + (g*u) @ Wf2^T
  { GemmP p{fG, FF,0,0, fWF2Q, FF,0,0, out, 512,0,0, (const float*)0, fXR, 512,0,0, 1.0f, CM,512,(int)FF,1};
    run_gemm<4,true>(p, stream, 1); }
}